// Round 4
// baseline (3547.098 us; speedup 1.0000x reference)
//
#include <hip/hip_runtime.h>

typedef unsigned int u32;
typedef unsigned short u16;
typedef unsigned long long u64;
typedef __attribute__((ext_vector_type(8))) short short8;
typedef __attribute__((ext_vector_type(4))) float f32x4;

#define SEQ 512
#define BATCH 32
#define DIM 1024
#define NB 128   // persistent blocks in recurrent kernel

// workspace layout (bytes)
#define OFF_XT    0ull                  // bf16 [16384][1024]  (row m = s*32+b)
#define OFF_UBT   33554432ull           // bf16 [4096][1024]   U^T concat (k_gemm B)
#define OFF_WG2   41943040ull           // bf16 [128 blk][32 ks][32 rr][32 kk] K-major tiled W
#define OFF_XPROJ 50331648ull           // bf16 [512][32][4096]
#define OFF_HBUF  184549376ull          // bf16 [2][32768] K-major tiled h
#define OFF_BIAS  184680448ull          // f32  [4096]
#define OFF_SYNC  184696832ull          // u32 flags[128] packed (8 cachelines)

__device__ __forceinline__ float bf2f(u16 u) {
  union { u32 u; float f; } v; v.u = ((u32)u) << 16; return v.f;
}
__device__ __forceinline__ u16 f2bf(float f) {
  union { float f; u32 u; } v; v.f = f;
  u32 r = v.u + 0x7FFFu + ((v.u >> 16) & 1u);
  return (u16)(r >> 16);
}
__device__ __forceinline__ void gload_lds16(const u16* g, u16* l) {
  __builtin_amdgcn_global_load_lds(
      (const __attribute__((address_space(1))) u32*)g,
      (__attribute__((address_space(3))) u32*)l, 16, 0, 0);
}
// LLC-coherent LDS-DMA: aux=17 = SC0|SC1 -> bypass L1+L2, read at LLC
__device__ __forceinline__ void gload_lds16_coh(const u16* g, u16* l) {
  __builtin_amdgcn_global_load_lds(
      (const __attribute__((address_space(1))) u32*)g,
      (__attribute__((address_space(3))) u32*)l, 16, 0, 17);
}

// ---------------- init: zero h buffers + flags, concat bias ---------------
__global__ void k_init(u32* hb, float* biasc, u32* sync,
                       const float* bi, const float* bfv,
                       const float* bo, const float* bg) {
  int i = blockIdx.x * 256 + threadIdx.x;
  if (i < 32768) {
    hb[i] = 0u;                       // both 64KB h buffers (128KB = 32768 u32)
  } else if (i < 32768 + 4096) {
    int e = i - 32768;
    int g = e >> 10, c = e & 1023;
    const float* p = (g == 0) ? bi : (g == 1) ? bfv : (g == 2) ? bo : bg;
    biasc[e] = p[c];
  } else if (i < 32768 + 4096 + 1024) {
    sync[i - 32768 - 4096] = 0u;      // 128 packed flags (zero 1024 for safety)
  }
}

// ---------------- transpose-cast the 8 weight matrices --------------------
// U matrices -> Ubt[e][k] row-major ([N][K] for k_gemm B operand)
// W matrices -> Wg2 K-major tiled per recurrent block:
//   off = blk*32768 + (k>>5)*1024 + rr*32 + (k&31),
//   rr = (gate<<3)|(c&7), blk = c>>3
__global__ void k_prep_w(const float* Ui, const float* Wi, const float* Uf,
                         const float* Wf, const float* Uo, const float* Wo,
                         const float* Ug, const float* Wg, u16* Ubt, u16* Wg2) {
  __shared__ float tile[64][65];
  int bx = blockIdx.x;
  int mi = bx >> 8;               // matrix 0..7 (Ui,Wi,Uf,Wf,Uo,Wo,Ug,Wg)
  int tt = bx & 255;
  int tr = tt >> 4, tc = tt & 15; // 16x16 grid of 64x64 tiles
  const float* src;
  switch (mi) {
    case 0: src = Ui; break; case 1: src = Wi; break;
    case 2: src = Uf; break; case 3: src = Wf; break;
    case 4: src = Uo; break; case 5: src = Wo; break;
    case 6: src = Ug; break; default: src = Wg; break;
  }
  int g = mi >> 1;
  int d0 = tr * 64, c0 = tc * 64;
  int ty = threadIdx.x >> 6, tx = threadIdx.x & 63;
#pragma unroll
  for (int i = 0; i < 16; ++i) {
    int r = i * 4 + ty;
    tile[r][tx] = src[(size_t)(d0 + r) * 1024 + c0 + tx];
  }
  __syncthreads();
  if (mi & 1) {
    // W matrix -> K-major tiled per-block slices
#pragma unroll
    for (int i = 0; i < 16; ++i) {
      int cc = i * 4 + ty;
      int c_full = c0 + cc;
      int k = d0 + tx;
      int blk = c_full >> 3;
      int rr = (g << 3) | (c_full & 7);
      Wg2[(size_t)blk * 32768 + ((k >> 5) << 10) + rr * 32 + (k & 31)] =
          f2bf(tile[tx][cc]);
    }
  } else {
    // U matrix -> [e][k] row-major
#pragma unroll
    for (int i = 0; i < 16; ++i) {
      int cc = i * 4 + ty;
      Ubt[(size_t)((g << 10) + c0 + cc) * 1024 + d0 + tx] = f2bf(tile[tx][cc]);
    }
  }
}

// ---------------- transpose-cast X: Xt[s*32+b][d] = X[b][s][d] ------------
__global__ void k_prep_x(const float* __restrict__ X, u16* __restrict__ Xt) {
  int idx = blockIdx.x * 256 + threadIdx.x;   // 4M threads, 4 elems each
  int m = idx >> 8, d4 = (idx & 255) << 2;
  int s = m >> 5, b = m & 31;
  const float4* p = (const float4*)(X + (size_t)(b * SEQ + s) * DIM + d4);
  float4 v = *p;
  u16 o[4] = { f2bf(v.x), f2bf(v.y), f2bf(v.z), f2bf(v.w) };
  *(ushort4*)(Xt + (size_t)m * DIM + d4) = *(ushort4*)o;
}

// ---------------- phase 1 GEMM: xproj = Xt @ U + bias  (m97 structure) ----
__global__ __launch_bounds__(256) void k_gemm(const u16* __restrict__ Xt,
                                              const u16* __restrict__ Ubt,
                                              const float* __restrict__ biasc,
                                              u16* __restrict__ xproj) {
  __shared__ u16 As[128 * 32];
  __shared__ u16 Bs[128 * 32];
  int tid = threadIdx.x;
  int w = tid >> 6, l = tid & 63;
  int n0 = blockIdx.x * 128, m0 = blockIdx.y * 128;
  int wm = w >> 1, wn = w & 1;
  int lrow = l & 15, lq = l >> 4;
  f32x4 acc[4][4] = {};
  for (int kt = 0; kt < 32; ++kt) {
    int k0 = kt * 32;
    __syncthreads();
#pragma unroll
    for (int is = 0; is < 2; ++is) {
      int c = is * 256 + w * 64 + l;
      int row = c >> 2, kg = c & 3;
      gload_lds16(Xt + (size_t)(m0 + row) * 1024 + k0 + kg * 8, As + c * 8);
      gload_lds16(Ubt + (size_t)(n0 + row) * 1024 + k0 + kg * 8, Bs + c * 8);
    }
    __syncthreads();
    short8 af[4], bf[4];
#pragma unroll
    for (int mt = 0; mt < 4; ++mt)
      af[mt] = *(const short8*)(As + (wm * 64 + mt * 16 + lrow) * 32 + lq * 8);
#pragma unroll
    for (int nt = 0; nt < 4; ++nt)
      bf[nt] = *(const short8*)(Bs + (wn * 64 + nt * 16 + lrow) * 32 + lq * 8);
#pragma unroll
    for (int mt = 0; mt < 4; ++mt)
#pragma unroll
      for (int nt = 0; nt < 4; ++nt)
        acc[mt][nt] = __builtin_amdgcn_mfma_f32_16x16x32_bf16(
            af[mt], bf[nt], acc[mt][nt], 0, 0, 0);
  }
#pragma unroll
  for (int nt = 0; nt < 4; ++nt) {
    int col = n0 + wn * 64 + nt * 16 + lrow;
    float bv = biasc[col];
#pragma unroll
    for (int mt = 0; mt < 4; ++mt) {
      int rbase = m0 + wm * 64 + mt * 16 + lq * 4;
#pragma unroll
      for (int r = 0; r < 4; ++r)
        xproj[(size_t)(rbase + r) * 4096 + col] = f2bf(acc[mt][nt][r] + bv);
    }
  }
}

// ---------------- phase 2: persistent recurrent kernel --------------------
// 128 blocks; block owns h-cols [blk*8, blk*8+8).
// Coherence protocol (NO __threadfence anywhere):
//   h stores  : wave0-only coalesced 8B relaxed agent atomics (write-through)
//   flag      : packed u32/block, stored by tid0 after wave0's own vmcnt drain
//   h loads   : global_load_lds aux=17 (SC0|SC1) -> read at LLC
// Handoff critical path is wave0-only: gates -> LDS hstage -> LDS barrier ->
// wave0 8B stores -> s_waitcnt vmcnt(0) -> flag -> poll. out-stores (HBM) are
// issued into the poll's shadow and drain at the post-poll barrier.
__global__ __launch_bounds__(256, 1) void k_rec(const u16* __restrict__ Wg2,
                                                const u16* __restrict__ xproj,
                                                u16* hbuf, float* out, u32* sync) {
  __shared__ u16 Ws[32 * 1024];     // 64KB, staged once
  __shared__ u16 Hs[32 * 1024];     // 64KB, re-staged per step
  __shared__ u16 XPs[32 * 32];      // 2KB x_proj slice
  __shared__ float zbuf[32][33];    // 4.2KB z tile
  __shared__ u16 hstage[256];       // 512B h staging for wave0 store
  int tid = threadIdx.x;
  int w = tid >> 6, l = tid & 63;
  int blk = blockIdx.x;
  int lrow = l & 15, lq = l >> 4;
  // stage W slice once: linear 64KB copy (already in per-block tiled order)
#pragma unroll
  for (int it = 0; it < 16; ++it) {
    int c = it * 256 + w * 64 + l;
    gload_lds16(Wg2 + (size_t)blk * 32768 + c * 8, Ws + c * 8);
  }
  float c_reg = 0.f;
  int eb = tid >> 3, ec = tid & 7;  // epilogue: thread owns (batch eb, hcol ec)
  int mt = w >> 1, nt = w & 1;      // wave tile assignment
  const u16* ap0 = Hs + (mt * 16 + lrow) * 32 + lq * 8;
  const u16* bp0 = Ws + (nt * 16 + lrow) * 32 + lq * 8;
  // wave0 h store: lane l stores 8B = hstage[l*4..l*4+3] -> tiled hbuf
  u16* hst8 = hbuf + ((blk >> 2) << 10) + (l >> 1) * 32 + ((blk & 3) << 3) +
              (l & 1) * 4;
  float* out_base = out + (size_t)eb * SEQ * DIM + (blk << 3) + ec;
  __syncthreads();

  for (int s = 0; s < SEQ; ++s) {
    // stage x_proj slice + h_prev (LLC-coherent DMA)
    if (w < 2) {
      int c2 = w * 64 + l;
      int b = c2 >> 2, g = c2 & 3;
      gload_lds16(xproj + (size_t)(s * 32 + b) * 4096 + (g << 10) + (blk << 3),
                  XPs + c2 * 8);
    }
    const u16* hsrc = hbuf + (size_t)(s & 1) * 32768;
#pragma unroll
    for (int it = 0; it < 16; ++it) {
      int c = it * 256 + w * 64 + l;
      gload_lds16_coh(hsrc + c * 8, Hs + c * 8);
    }
    __syncthreads();                 // SYNC-D: DMA drained, LDS staged

    // z = h_prev @ W_slice : wave (mt,nt) computes 16x16 tile.
    // Two independent accumulator chains (even/odd k-slab) halve dep latency.
    f32x4 acc0 = { 0.f, 0.f, 0.f, 0.f };
    f32x4 acc1 = { 0.f, 0.f, 0.f, 0.f };
#pragma unroll
    for (int ks = 0; ks < 16; ++ks) {
      short8 a0 = *(const short8*)(ap0 + (2 * ks) * 1024);
      short8 b0 = *(const short8*)(bp0 + (2 * ks) * 1024);
      short8 a1 = *(const short8*)(ap0 + (2 * ks + 1) * 1024);
      short8 b1 = *(const short8*)(bp0 + (2 * ks + 1) * 1024);
      acc0 = __builtin_amdgcn_mfma_f32_16x16x32_bf16(a0, b0, acc0, 0, 0, 0);
      acc1 = __builtin_amdgcn_mfma_f32_16x16x32_bf16(a1, b1, acc1, 0, 0, 0);
    }
    f32x4 acc = acc0 + acc1;
    {
      int col = nt * 16 + lrow;
      int rb = mt * 16 + lq * 4;
#pragma unroll
      for (int r = 0; r < 4; ++r) zbuf[rb + r][col] = acc[r];
    }
    __syncthreads();                 // SYNC-A: zbuf ready

    // gates: zbuf cols 0-7=i, 8-15=f, 16-23=o, 24-31=g
    float zi = zbuf[eb][ec]      + bf2f(XPs[eb * 32 + ec]);
    float zf = zbuf[eb][8 + ec]  + bf2f(XPs[eb * 32 + 8 + ec]);
    float zo = zbuf[eb][16 + ec] + bf2f(XPs[eb * 32 + 16 + ec]);
    float zg = zbuf[eb][24 + ec] + bf2f(XPs[eb * 32 + 24 + ec]);
    float ig = 1.f / (1.f + __expf(-zi));
    float fg = 1.f / (1.f + __expf(-zf));
    float og = 1.f / (1.f + __expf(-zo));
    float gg = tanhf(zg);
    c_reg = 1.f / (1.f + __expf(-(fg * c_reg + ig * gg)));  // nonstandard cell
    float h = tanhf(c_reg) * og;
    hstage[tid] = f2bf(h);
    __syncthreads();                 // SYNC-B: LDS-only (nothing global in flight)

    if (w != 0)                      // waves 1-3: out-store drains during poll
      __builtin_nontemporal_store(h, out_base + (size_t)s * DIM);

    if (w == 0) {
      // coalesced 8B write-through h store, own-wave drain, flag, poll
      u64 hv = *(const u64*)(hstage + l * 4);
      __hip_atomic_store((u64*)(hst8 + (size_t)(((s + 1) & 1)) * 32768), hv,
                         __ATOMIC_RELAXED, __HIP_MEMORY_SCOPE_AGENT);
      asm volatile("s_waitcnt vmcnt(0)" ::: "memory");
      if (l == 0)
        __hip_atomic_store(sync + blk, (u32)(s + 1), __ATOMIC_RELAXED,
                           __HIP_MEMORY_SCOPE_AGENT);
      __builtin_nontemporal_store(h, out_base + (size_t)s * DIM);
      u32 tgt = (u32)(s + 1);
      int guard = 0;
      for (;;) {
        u32 a = __hip_atomic_load(sync + l, __ATOMIC_RELAXED,
                                  __HIP_MEMORY_SCOPE_AGENT);
        u32 b = __hip_atomic_load(sync + 64 + l, __ATOMIC_RELAXED,
                                  __HIP_MEMORY_SCOPE_AGENT);
        if (a >= tgt && b >= tgt) break;
        __builtin_amdgcn_s_sleep(1);
        if (++guard > 20000000) break;   // anti-hang bailout
      }
    }
    asm volatile("" ::: "memory");   // no hoisting h loads above the poll
    __syncthreads();                 // SYNC-C: all released; out-stores retired
  }
}

// ---------------------------------------------------------------------------
extern "C" void kernel_launch(void* const* d_in, const int* in_sizes, int n_in,
                              void* d_out, int out_size, void* d_ws,
                              size_t ws_size, hipStream_t stream) {
  const float* X   = (const float*)d_in[0];
  const float* Ui  = (const float*)d_in[1];
  const float* Wi  = (const float*)d_in[2];
  const float* Uf  = (const float*)d_in[3];
  const float* Wf  = (const float*)d_in[4];
  const float* Uo  = (const float*)d_in[5];
  const float* Wo  = (const float*)d_in[6];
  const float* Ug  = (const float*)d_in[7];
  const float* Wg  = (const float*)d_in[8];
  const float* bi  = (const float*)d_in[9];
  const float* bfv = (const float*)d_in[10];
  const float* bo  = (const float*)d_in[11];
  const float* bg  = (const float*)d_in[12];
  char* ws = (char*)d_ws;
  u16* Xt      = (u16*)(ws + OFF_XT);
  u16* Ubt     = (u16*)(ws + OFF_UBT);
  u16* Wg2     = (u16*)(ws + OFF_WG2);
  u16* xproj   = (u16*)(ws + OFF_XPROJ);
  u16* hbuf    = (u16*)(ws + OFF_HBUF);
  float* biasc = (float*)(ws + OFF_BIAS);
  u32* sync    = (u32*)(ws + OFF_SYNC);
  float* out   = (float*)d_out;

  k_init<<<152, 256, 0, stream>>>((u32*)hbuf, biasc, sync, bi, bfv, bo, bg);
  k_prep_w<<<2048, 256, 0, stream>>>(Ui, Wi, Uf, Wf, Uo, Wo, Ug, Wg, Ubt, Wg2);
  k_prep_x<<<16384, 256, 0, stream>>>(X, Xt);
  k_gemm<<<dim3(32, 128), 256, 0, stream>>>(Xt, Ubt, biasc, xproj);
  k_rec<<<NB, 256, 0, stream>>>(Wg2, xproj, hbuf, out, sync);
}

// Round 5
// 1935.988 us; speedup vs baseline: 1.8322x; 1.8322x over previous
//
#include <hip/hip_runtime.h>

typedef unsigned int u32;
typedef unsigned short u16;
typedef unsigned long long u64;
typedef __attribute__((ext_vector_type(8))) short short8;
typedef __attribute__((ext_vector_type(4))) float f32x4;

#define SEQ 512
#define BATCH 32
#define DIM 1024
#define NB 128   // persistent blocks in recurrent kernel

// workspace layout (bytes)
#define OFF_XT    0ull                  // bf16 [16384][1024]  (row m = s*32+b)
#define OFF_UBT   33554432ull           // bf16 [4096][1024]   U^T concat (k_gemm B)
#define OFF_WG2   41943040ull           // bf16 [128 blk][32 ks][32 rr][32 kk] K-major tiled W
#define OFF_XPROJ 50331648ull           // bf16 [512][32][4096]
#define OFF_HBUF  184549376ull          // bf16 [2][32768] K-major tiled h
#define OFF_BIAS  184680448ull          // f32  [4096]
#define OFF_SYNC  184696832ull          // u32 flags[128*32] (128B-padded!)

__device__ __forceinline__ float bf2f(u16 u) {
  union { u32 u; float f; } v; v.u = ((u32)u) << 16; return v.f;
}
__device__ __forceinline__ u16 f2bf(float f) {
  union { float f; u32 u; } v; v.f = f;
  u32 r = v.u + 0x7FFFu + ((v.u >> 16) & 1u);
  return (u16)(r >> 16);
}
__device__ __forceinline__ void gload_lds16(const u16* g, u16* l) {
  __builtin_amdgcn_global_load_lds(
      (const __attribute__((address_space(1))) u32*)g,
      (__attribute__((address_space(3))) u32*)l, 16, 0, 0);
}
// LLC-coherent LDS-DMA: aux=17 = SC0|SC1 -> bypass L1+L2, read at LLC
__device__ __forceinline__ void gload_lds16_coh(const u16* g, u16* l) {
  __builtin_amdgcn_global_load_lds(
      (const __attribute__((address_space(1))) u32*)g,
      (__attribute__((address_space(3))) u32*)l, 16, 0, 17);
}

// ---------------- init: zero h buffers + flags, concat bias ---------------
__global__ void k_init(u32* hb, float* biasc, u32* sync,
                       const float* bi, const float* bfv,
                       const float* bo, const float* bg) {
  int i = blockIdx.x * 256 + threadIdx.x;
  if (i < 32768) {
    hb[i] = 0u;                       // both 64KB h buffers (128KB = 32768 u32)
  } else if (i < 32768 + 4096) {
    int e = i - 32768;
    int g = e >> 10, c = e & 1023;
    const float* p = (g == 0) ? bi : (g == 1) ? bfv : (g == 2) ? bo : bg;
    biasc[e] = p[c];
  } else if (i < 32768 + 4096 + 4096) {
    sync[i - 32768 - 4096] = 0u;      // 128 flags padded to 128B each
  }
}

// ---------------- transpose-cast the 8 weight matrices --------------------
// U matrices -> Ubt[e][k] row-major ([N][K] for k_gemm B operand)
// W matrices -> Wg2 K-major tiled per recurrent block:
//   off = blk*32768 + (k>>5)*1024 + rr*32 + (k&31),
//   rr = (gate<<3)|(c&7), blk = c>>3
__global__ void k_prep_w(const float* Ui, const float* Wi, const float* Uf,
                         const float* Wf, const float* Uo, const float* Wo,
                         const float* Ug, const float* Wg, u16* Ubt, u16* Wg2) {
  __shared__ float tile[64][65];
  int bx = blockIdx.x;
  int mi = bx >> 8;               // matrix 0..7 (Ui,Wi,Uf,Wf,Uo,Wo,Ug,Wg)
  int tt = bx & 255;
  int tr = tt >> 4, tc = tt & 15; // 16x16 grid of 64x64 tiles
  const float* src;
  switch (mi) {
    case 0: src = Ui; break; case 1: src = Wi; break;
    case 2: src = Uf; break; case 3: src = Wf; break;
    case 4: src = Uo; break; case 5: src = Wo; break;
    case 6: src = Ug; break; default: src = Wg; break;
  }
  int g = mi >> 1;
  int d0 = tr * 64, c0 = tc * 64;
  int ty = threadIdx.x >> 6, tx = threadIdx.x & 63;
#pragma unroll
  for (int i = 0; i < 16; ++i) {
    int r = i * 4 + ty;
    tile[r][tx] = src[(size_t)(d0 + r) * 1024 + c0 + tx];
  }
  __syncthreads();
  if (mi & 1) {
    // W matrix -> K-major tiled per-block slices
#pragma unroll
    for (int i = 0; i < 16; ++i) {
      int cc = i * 4 + ty;
      int c_full = c0 + cc;
      int k = d0 + tx;
      int blk = c_full >> 3;
      int rr = (g << 3) | (c_full & 7);
      Wg2[(size_t)blk * 32768 + ((k >> 5) << 10) + rr * 32 + (k & 31)] =
          f2bf(tile[tx][cc]);
    }
  } else {
    // U matrix -> [e][k] row-major
#pragma unroll
    for (int i = 0; i < 16; ++i) {
      int cc = i * 4 + ty;
      Ubt[(size_t)((g << 10) + c0 + cc) * 1024 + d0 + tx] = f2bf(tile[tx][cc]);
    }
  }
}

// ---------------- transpose-cast X: Xt[s*32+b][d] = X[b][s][d] ------------
__global__ void k_prep_x(const float* __restrict__ X, u16* __restrict__ Xt) {
  int idx = blockIdx.x * 256 + threadIdx.x;   // 4M threads, 4 elems each
  int m = idx >> 8, d4 = (idx & 255) << 2;
  int s = m >> 5, b = m & 31;
  const float4* p = (const float4*)(X + (size_t)(b * SEQ + s) * DIM + d4);
  float4 v = *p;
  u16 o[4] = { f2bf(v.x), f2bf(v.y), f2bf(v.z), f2bf(v.w) };
  *(ushort4*)(Xt + (size_t)m * DIM + d4) = *(ushort4*)o;
}

// ---------------- phase 1 GEMM: xproj = Xt @ U + bias  (m97 structure) ----
__global__ __launch_bounds__(256) void k_gemm(const u16* __restrict__ Xt,
                                              const u16* __restrict__ Ubt,
                                              const float* __restrict__ biasc,
                                              u16* __restrict__ xproj) {
  __shared__ u16 As[128 * 32];
  __shared__ u16 Bs[128 * 32];
  int tid = threadIdx.x;
  int w = tid >> 6, l = tid & 63;
  int n0 = blockIdx.x * 128, m0 = blockIdx.y * 128;
  int wm = w >> 1, wn = w & 1;
  int lrow = l & 15, lq = l >> 4;
  f32x4 acc[4][4] = {};
  for (int kt = 0; kt < 32; ++kt) {
    int k0 = kt * 32;
    __syncthreads();
#pragma unroll
    for (int is = 0; is < 2; ++is) {
      int c = is * 256 + w * 64 + l;
      int row = c >> 2, kg = c & 3;
      gload_lds16(Xt + (size_t)(m0 + row) * 1024 + k0 + kg * 8, As + c * 8);
      gload_lds16(Ubt + (size_t)(n0 + row) * 1024 + k0 + kg * 8, Bs + c * 8);
    }
    __syncthreads();
    short8 af[4], bf[4];
#pragma unroll
    for (int mt = 0; mt < 4; ++mt)
      af[mt] = *(const short8*)(As + (wm * 64 + mt * 16 + lrow) * 32 + lq * 8);
#pragma unroll
    for (int nt = 0; nt < 4; ++nt)
      bf[nt] = *(const short8*)(Bs + (wn * 64 + nt * 16 + lrow) * 32 + lq * 8);
#pragma unroll
    for (int mt = 0; mt < 4; ++mt)
#pragma unroll
      for (int nt = 0; nt < 4; ++nt)
        acc[mt][nt] = __builtin_amdgcn_mfma_f32_16x16x32_bf16(
            af[mt], bf[nt], acc[mt][nt], 0, 0, 0);
  }
#pragma unroll
  for (int nt = 0; nt < 4; ++nt) {
    int col = n0 + wn * 64 + nt * 16 + lrow;
    float bv = biasc[col];
#pragma unroll
    for (int mt = 0; mt < 4; ++mt) {
      int rbase = m0 + wm * 64 + mt * 16 + lq * 4;
#pragma unroll
      for (int r = 0; r < 4; ++r)
        xproj[(size_t)(rbase + r) * 4096 + col] = f2bf(acc[mt][nt][r] + bv);
    }
  }
}

// ---------------- phase 2: persistent recurrent kernel --------------------
// R3 structure (padded flags, all-thread write-through h stores, LLC-coherent
// h DMA) with ONE critical-path change vs R3: out-stores (HBM, ~0.5-0.9us ack)
// are issued AFTER SYNC-B + flag, so they retire in the poll's shadow instead
// of gating the flag store. Plus: dual MFMA chains, xproj[s+1] prefetch in the
// poll window.
__global__ __launch_bounds__(256, 1) void k_rec(const u16* __restrict__ Wg2,
                                                const u16* __restrict__ xproj,
                                                u16* hbuf, float* out, u32* sync) {
  __shared__ u16 Ws[32 * 1024];     // 64KB, staged once
  __shared__ u16 Hs[32 * 1024];     // 64KB, re-staged per step
  __shared__ u16 XPs[32 * 32];      // 2KB x_proj slice (prefetched)
  __shared__ float zbuf[32][33];    // 4.2KB z tile
  int tid = threadIdx.x;
  int w = tid >> 6, l = tid & 63;
  int blk = blockIdx.x;
  int lrow = l & 15, lq = l >> 4;
  // stage W slice once: linear 64KB copy (already in per-block tiled order)
#pragma unroll
  for (int it = 0; it < 16; ++it) {
    int c = it * 256 + w * 64 + l;
    gload_lds16(Wg2 + (size_t)blk * 32768 + c * 8, Ws + c * 8);
  }
  // prefetch xproj slice for s=0
  if (w < 2) {
    int c2 = w * 64 + l;
    int b = c2 >> 2, g = c2 & 3;
    gload_lds16(xproj + (size_t)b * 4096 + (g << 10) + (blk << 3), XPs + c2 * 8);
  }
  float c_reg = 0.f;
  int eb = tid >> 3, ec = tid & 7;  // epilogue: thread owns (batch eb, hcol ec)
  int mt = w >> 1, nt = w & 1;      // wave tile assignment
  const u16* ap0 = Hs + (mt * 16 + lrow) * 32 + lq * 8;
  const u16* bp0 = Ws + (nt * 16 + lrow) * 32 + lq * 8;
  // h store address (K-major tiled, d = blk*8+ec)
  u16* hst_base = hbuf + ((blk >> 2) << 10) + eb * 32 + ((blk & 3) << 3) + ec;
  float* out_base = out + (size_t)eb * SEQ * DIM + (blk << 3) + ec;
  __syncthreads();

  for (int s = 0; s < SEQ; ++s) {
    // stage h_prev (LLC-coherent DMA); xproj slice was prefetched last step
    const u16* hsrc = hbuf + (size_t)(s & 1) * 32768;
#pragma unroll
    for (int it = 0; it < 16; ++it) {
      int c = it * 256 + w * 64 + l;
      gload_lds16_coh(hsrc + c * 8, Hs + c * 8);
    }
    __syncthreads();                 // SYNC-D: DMA drained, LDS staged

    // z = h_prev @ W_slice : wave (mt,nt) computes 16x16 tile.
    // Two independent accumulator chains halve MFMA dep-latency tail.
    f32x4 acc0 = { 0.f, 0.f, 0.f, 0.f };
    f32x4 acc1 = { 0.f, 0.f, 0.f, 0.f };
#pragma unroll
    for (int ks = 0; ks < 16; ++ks) {
      short8 a0 = *(const short8*)(ap0 + (2 * ks) * 1024);
      short8 b0 = *(const short8*)(bp0 + (2 * ks) * 1024);
      short8 a1 = *(const short8*)(ap0 + (2 * ks + 1) * 1024);
      short8 b1 = *(const short8*)(bp0 + (2 * ks + 1) * 1024);
      acc0 = __builtin_amdgcn_mfma_f32_16x16x32_bf16(a0, b0, acc0, 0, 0, 0);
      acc1 = __builtin_amdgcn_mfma_f32_16x16x32_bf16(a1, b1, acc1, 0, 0, 0);
    }
    f32x4 acc = acc0 + acc1;
    {
      int col = nt * 16 + lrow;
      int rb = mt * 16 + lq * 4;
#pragma unroll
      for (int r = 0; r < 4; ++r) zbuf[rb + r][col] = acc[r];
    }
    __syncthreads();                 // SYNC-A: zbuf ready

    // gates: zbuf cols 0-7=i, 8-15=f, 16-23=o, 24-31=g
    float zi = zbuf[eb][ec]      + bf2f(XPs[eb * 32 + ec]);
    float zf = zbuf[eb][8 + ec]  + bf2f(XPs[eb * 32 + 8 + ec]);
    float zo = zbuf[eb][16 + ec] + bf2f(XPs[eb * 32 + 16 + ec]);
    float zg = zbuf[eb][24 + ec] + bf2f(XPs[eb * 32 + 24 + ec]);
    float ig = 1.f / (1.f + __expf(-zi));
    float fg = 1.f / (1.f + __expf(-zf));
    float og = 1.f / (1.f + __expf(-zo));
    float gg = tanhf(zg);
    c_reg = 1.f / (1.f + __expf(-(fg * c_reg + ig * gg)));  // nonstandard cell
    float h = tanhf(c_reg) * og;
    // write-through h store only (LLC ack ~0.4us) -> SYNC-B stays cheap
    __hip_atomic_store(hst_base + (size_t)(((s + 1) & 1)) * 32768, f2bf(h),
                       __ATOMIC_RELAXED, __HIP_MEMORY_SCOPE_AGENT);
    __syncthreads();                 // SYNC-B: h stores drained (vmcnt0/wave)

    if (tid == 0)
      __hip_atomic_store(sync + blk * 32, (u32)(s + 1), __ATOMIC_RELAXED,
                         __HIP_MEMORY_SCOPE_AGENT);
    // xproj prefetch for next step: no flag dependency, flies during poll
    {
      int sp = (s + 1 < SEQ) ? s + 1 : s;
      if (w < 2) {
        int c2 = w * 64 + l;
        int b = c2 >> 2, g = c2 & 3;
        gload_lds16(xproj + (size_t)(sp * 32 + b) * 4096 + (g << 10) + (blk << 3),
                    XPs + c2 * 8);
      }
    }
    // out-store AFTER flag: HBM ack drains in the poll's shadow
    __builtin_nontemporal_store(h, out_base + (size_t)s * DIM);

    if (w == 0) {                    // wave0 polls: lane l covers flags l, l+64
      u32 tgt = (u32)(s + 1);
      int guard = 0;
      for (;;) {
        u32 a = __hip_atomic_load(sync + l * 32, __ATOMIC_RELAXED,
                                  __HIP_MEMORY_SCOPE_AGENT);
        u32 b = __hip_atomic_load(sync + (64 + l) * 32, __ATOMIC_RELAXED,
                                  __HIP_MEMORY_SCOPE_AGENT);
        if (a >= tgt && b >= tgt) break;
        __builtin_amdgcn_s_sleep(1);
        if (++guard > 20000000) break;   // anti-hang bailout
      }
    }
    asm volatile("" ::: "memory");   // no hoisting h loads above the poll
    __syncthreads();                 // SYNC-C: all released; out-stores retired
  }
}

// ---------------------------------------------------------------------------
extern "C" void kernel_launch(void* const* d_in, const int* in_sizes, int n_in,
                              void* d_out, int out_size, void* d_ws,
                              size_t ws_size, hipStream_t stream) {
  const float* X   = (const float*)d_in[0];
  const float* Ui  = (const float*)d_in[1];
  const float* Wi  = (const float*)d_in[2];
  const float* Uf  = (const float*)d_in[3];
  const float* Wf  = (const float*)d_in[4];
  const float* Uo  = (const float*)d_in[5];
  const float* Wo  = (const float*)d_in[6];
  const float* Ug  = (const float*)d_in[7];
  const float* Wg  = (const float*)d_in[8];
  const float* bi  = (const float*)d_in[9];
  const float* bfv = (const float*)d_in[10];
  const float* bo  = (const float*)d_in[11];
  const float* bg  = (const float*)d_in[12];
  char* ws = (char*)d_ws;
  u16* Xt      = (u16*)(ws + OFF_XT);
  u16* Ubt     = (u16*)(ws + OFF_UBT);
  u16* Wg2     = (u16*)(ws + OFF_WG2);
  u16* xproj   = (u16*)(ws + OFF_XPROJ);
  u16* hbuf    = (u16*)(ws + OFF_HBUF);
  float* biasc = (float*)(ws + OFF_BIAS);
  u32* sync    = (u32*)(ws + OFF_SYNC);
  float* out   = (float*)d_out;

  k_init<<<160, 256, 0, stream>>>((u32*)hbuf, biasc, sync, bi, bfv, bo, bg);
  k_prep_w<<<2048, 256, 0, stream>>>(Ui, Wi, Uf, Wf, Uo, Wo, Ug, Wg, Ubt, Wg2);
  k_prep_x<<<16384, 256, 0, stream>>>(X, Xt);
  k_gemm<<<dim3(32, 128), 256, 0, stream>>>(Xt, Ubt, biasc, xproj);
  k_rec<<<NB, 256, 0, stream>>>(Wg2, xproj, hbuf, out, sync);
}